// Round 1
// baseline (826.396 us; speedup 1.0000x reference)
//
#include <hip/hip_runtime.h>
#include <hip/hip_bf16.h>
#include <cstddef>
#include <cstdint>

// ---------------------------------------------------------------- types
typedef __bf16 bf16_t;
typedef __attribute__((ext_vector_type(8))) __bf16 bf16x8;
typedef __attribute__((ext_vector_type(4))) float f32x4;

#define B_  64
#define T_  2048
#define E_  512
#define H_  32
#define G_  96          // 3*H
#define N2_ 192         // both directions
#define OUT_ 131

// ---------------------------------------------------------------- fast math
__device__ __forceinline__ float fsig(float x) {
    // sigmoid(x) = 1 / (1 + 2^(-x*log2e))
    float e = __builtin_amdgcn_exp2f(-1.4426950408889634f * x);
    return __builtin_amdgcn_rcpf(1.0f + e);
}
__device__ __forceinline__ float ftanh(float x) {
    // tanh(x) = 1 - 2/(1 + 2^(2x*log2e)) ; saturates correctly at +-inf
    float e = __builtin_amdgcn_exp2f(2.8853900817779268f * x);
    return 1.0f - 2.0f * __builtin_amdgcn_rcpf(1.0f + e);
}

// ---------------------------------------------------------------- prep: W_ih -> bf16, pack biases
__global__ void prep_kernel(const float* __restrict__ Wf, const float* __restrict__ Wb,
                            const float* __restrict__ bf_, const float* __restrict__ bb_,
                            bf16_t* __restrict__ Wbf, float* __restrict__ bias) {
    int idx = blockIdx.x * 256 + threadIdx.x;        // 0 .. 98303
    int g = idx >> 9, k = idx & 511;
    float v = (g < G_) ? Wf[g * E_ + k] : Wb[(g - G_) * E_ + k];
    Wbf[idx] = (bf16_t)v;
    if (idx < N2_) bias[idx] = (idx < G_) ? bf_[idx] : bb_[idx - G_];
}

// ---------------------------------------------------------------- projection GEMM
// xp[m][n] = sum_k x[m][k] * W[n][k] + bias[n],  m = b*T + t, n in [0,192)
__global__ __launch_bounds__(256) void proj_kernel(
    const float* __restrict__ x,        // [131072][512] f32
    const bf16_t* __restrict__ Wbf,     // [192][512] bf16
    const float* __restrict__ bias,     // [192]
    float* __restrict__ xp)             // [131072][192] f32
{
    __shared__ bf16_t Alds[64][72];     // +8 pad -> 144B rows, 16B aligned
    __shared__ bf16_t Blds[96][72];

    const int tid  = threadIdx.x;
    const int lane = tid & 63;
    const int w    = tid >> 6;          // wave 0..3
    const int wm   = w & 1;             // 2 waves in M
    const int wn   = w >> 1;            // 2 waves in N
    const int m0   = blockIdx.x * 64;
    const int n0   = blockIdx.y * 96;

    const int arow = tid >> 2;          // 0..63
    const int acol = (tid & 3) * 16;    // 0,16,32,48

    f32x4 acc[2][3];
    #pragma unroll
    for (int i = 0; i < 2; ++i)
        #pragma unroll
        for (int jn = 0; jn < 3; ++jn)
            acc[i][jn] = (f32x4){0.f, 0.f, 0.f, 0.f};

    for (int kt = 0; kt < 8; ++kt) {
        const int c0 = kt * 64;
        __syncthreads();
        // ---- stage A (f32 -> bf16), 16 elems/thread
        {
            const float* asrc = x + (size_t)(m0 + arow) * E_ + c0 + acol;
            float4 v0 = *(const float4*)(asrc + 0);
            float4 v1 = *(const float4*)(asrc + 4);
            float4 v2 = *(const float4*)(asrc + 8);
            float4 v3 = *(const float4*)(asrc + 12);
            bf16x8 pa, pb;
            pa[0]=(bf16_t)v0.x; pa[1]=(bf16_t)v0.y; pa[2]=(bf16_t)v0.z; pa[3]=(bf16_t)v0.w;
            pa[4]=(bf16_t)v1.x; pa[5]=(bf16_t)v1.y; pa[6]=(bf16_t)v1.z; pa[7]=(bf16_t)v1.w;
            pb[0]=(bf16_t)v2.x; pb[1]=(bf16_t)v2.y; pb[2]=(bf16_t)v2.z; pb[3]=(bf16_t)v2.w;
            pb[4]=(bf16_t)v3.x; pb[5]=(bf16_t)v3.y; pb[6]=(bf16_t)v3.z; pb[7]=(bf16_t)v3.w;
            *(bf16x8*)&Alds[arow][acol]     = pa;
            *(bf16x8*)&Alds[arow][acol + 8] = pb;
        }
        // ---- stage B (already bf16): 96 rows x 64 k = 768 units of 8 bf16
        #pragma unroll
        for (int i = 0; i < 3; ++i) {
            int u = tid + i * 256;
            int brow = u >> 3, koff = (u & 7) * 8;
            bf16x8 bv = *(const bf16x8*)(Wbf + (size_t)(n0 + brow) * E_ + c0 + koff);
            *(bf16x8*)&Blds[brow][koff] = bv;
        }
        __syncthreads();
        // ---- MFMA
        #pragma unroll
        for (int ks = 0; ks < 2; ++ks) {
            bf16x8 af[2], bfr[3];
            #pragma unroll
            for (int i = 0; i < 2; ++i)
                af[i] = *(const bf16x8*)&Alds[wm * 32 + i * 16 + (lane & 15)][ks * 32 + (lane >> 4) * 8];
            #pragma unroll
            for (int jn = 0; jn < 3; ++jn)
                bfr[jn] = *(const bf16x8*)&Blds[wn * 48 + jn * 16 + (lane & 15)][ks * 32 + (lane >> 4) * 8];
            #pragma unroll
            for (int i = 0; i < 2; ++i)
                #pragma unroll
                for (int jn = 0; jn < 3; ++jn)
                    acc[i][jn] = __builtin_amdgcn_mfma_f32_16x16x32_bf16(af[i], bfr[jn], acc[i][jn], 0, 0, 0);
        }
    }
    // ---- epilogue: C[row=(lane>>4)*4+r][col=lane&15]
    #pragma unroll
    for (int i = 0; i < 2; ++i)
        #pragma unroll
        for (int jn = 0; jn < 3; ++jn)
            #pragma unroll
            for (int r = 0; r < 4; ++r) {
                int mg = m0 + wm * 32 + i * 16 + (lane >> 4) * 4 + r;
                int ng = n0 + wn * 48 + jn * 16 + (lane & 15);
                xp[(size_t)mg * N2_ + ng] = acc[i][jn][r] + bias[ng];
            }
}

// ---------------------------------------------------------------- GRU recurrence
// 1 wave per chain. lane = j + 32*p ; lane owns h[j] (replicated over p),
// computes the k-half p of the three dot products.
__global__ __launch_bounds__(64) void gru_rec_kernel(
    const float* __restrict__ xp,       // [B*T*192]
    const int*   __restrict__ src_len,  // [B]
    const float* __restrict__ Whh_f, const float* __restrict__ bhh_f,
    const float* __restrict__ Whh_b, const float* __restrict__ bhh_b,
    float* __restrict__ hout)           // [B][64]  (fwd 0..31, bwd 32..63)
{
    const int blk  = blockIdx.x;
    const int b    = blk >> 1;
    const int dir  = blk & 1;
    const int lane = threadIdx.x;
    const int j    = lane & 31;
    const int p    = lane >> 5;

    const float* Whh = dir ? Whh_b : Whh_f;
    const float* bhh = dir ? bhh_b : bhh_f;

    // per-lane slice of W_hh rows (r,z,n) over k in [16p, 16p+16)
    float wr[16], wz[16], wn[16];
    #pragma unroll
    for (int i = 0; i < 16; ++i) {
        int k = p * 16 + i;
        wr[i] = Whh[(j)      * H_ + k];
        wz[i] = Whh[(32 + j) * H_ + k];
        wn[i] = Whh[(64 + j) * H_ + k];
    }
    // half-bias seeds (each k-half contributes 0.5*b, sum after reduce = b)
    const float br2 = 0.5f * bhh[j];
    const float bz2 = 0.5f * bhh[32 + j];
    const float bn2 = 0.5f * bhh[64 + j];

    // bpermute byte addresses: source lanes 0..31 hold h[0..31]
    int ba[16];
    #pragma unroll
    for (int k = 0; k < 16; ++k) ba[k] = ((lane & 32) << 1) + 4 * k;  // lane 16p+k
    const int bx = (lane ^ 32) << 2;                                   // xor-32 partner

    int len = src_len[b];
    if (len < 1) len = 1;
    if (len > T_) len = T_;
    const int sd = dir ? -1 : 1;
    const int t0 = dir ? (len - 1) : 0;
    const int rowbase = b * (T_ * N2_) + dir * G_ + j;

    float h = 0.0f;

    auto loadq = [&](int q, float& xr, float& xz, float& xn) {
        int t = t0 + sd * q;
        if (t < 0) t = 0;
        if (t > T_ - 1) t = T_ - 1;
        const float* ps = xp + rowbase + t * N2_;
        xr = ps[0]; xz = ps[32]; xn = ps[64];
    };

    auto step = [&](float xr, float xz, float xn) {
        int hi = __float_as_int(h);
        float hk[16];
        #pragma unroll
        for (int k = 0; k < 16; ++k)
            hk[k] = __int_as_float(__builtin_amdgcn_ds_bpermute(ba[k], hi));
        float ar = br2, az = bz2, an = bn2;
        #pragma unroll
        for (int k = 0; k < 16; ++k) {
            ar = __builtin_fmaf(hk[k], wr[k], ar);
            az = __builtin_fmaf(hk[k], wz[k], az);
            an = __builtin_fmaf(hk[k], wn[k], an);
        }
        ar += __int_as_float(__builtin_amdgcn_ds_bpermute(bx, __float_as_int(ar)));
        az += __int_as_float(__builtin_amdgcn_ds_bpermute(bx, __float_as_int(az)));
        an += __int_as_float(__builtin_amdgcn_ds_bpermute(bx, __float_as_int(an)));
        float r = fsig(xr + ar);
        float z = fsig(xz + az);
        float n = ftanh(__builtin_fmaf(r, an, xn));
        h = __builtin_fmaf(z, h - n, n);            // (1-z)*n + z*h
    };

    // 4-deep software pipeline with static register buffers
    float bxr[4], bxz[4], bxn[4];
    #pragma unroll
    for (int d = 0; d < 4; ++d) {
        int q = d; if (q > len - 1) q = len - 1;
        loadq(q, bxr[d], bxz[d], bxn[d]);
    }
    int s = 0;
    while (s + 4 <= len) {
        #pragma unroll
        for (int d = 0; d < 4; ++d) {
            step(bxr[d], bxz[d], bxn[d]);
            int q = s + d + 4; if (q > len - 1) q = len - 1;
            loadq(q, bxr[d], bxz[d], bxn[d]);
        }
        s += 4;
    }
    #pragma unroll
    for (int d = 0; d < 4; ++d)
        if (s + d < len) step(bxr[d], bxz[d], bxn[d]);

    if (p == 0) hout[b * 64 + dir * 32 + j] = h;
}

// ---------------------------------------------------------------- final fc
__global__ __launch_bounds__(192) void fc_kernel(
    const float* __restrict__ hbuf,     // [64][64]
    const float* __restrict__ fcW,      // [131][64]
    const float* __restrict__ fcb,      // [131]
    float* __restrict__ out)            // [64][131]
{
    __shared__ float hrow[64];
    const int b = blockIdx.x, tid = threadIdx.x;
    if (tid < 64) hrow[tid] = hbuf[b * 64 + tid];
    __syncthreads();
    if (tid < OUT_) {
        float acc = fcb[tid];
        #pragma unroll
        for (int i = 0; i < 64; ++i)
            acc = __builtin_fmaf(hrow[i], fcW[tid * 64 + i], acc);
        out[b * OUT_ + tid] = acc;
    }
}

// ---------------------------------------------------------------- launch
extern "C" void kernel_launch(void* const* d_in, const int* in_sizes, int n_in,
                              void* d_out, int out_size, void* d_ws, size_t ws_size,
                              hipStream_t stream) {
    const float* x    = (const float*)d_in[0];
    const int*   srcl = (const int*)  d_in[1];
    // d_in[2] = other_input (unused by reference)
    const float* Wihf = (const float*)d_in[3];
    const float* Whhf = (const float*)d_in[4];
    const float* bihf = (const float*)d_in[5];
    const float* bhhf = (const float*)d_in[6];
    const float* Wihb = (const float*)d_in[7];
    const float* Whhb = (const float*)d_in[8];
    const float* bihb = (const float*)d_in[9];
    const float* bhhb = (const float*)d_in[10];
    const float* fcW  = (const float*)d_in[11];
    const float* fcb  = (const float*)d_in[12];
    float* out = (float*)d_out;

    const size_t XP_BYTES   = (size_t)B_ * T_ * N2_ * 4;   // 100,663,296
    const size_t HBUF_BYTES = (size_t)B_ * 64 * 4;         // 16,384
    const size_t BIAS_BYTES = 1024;
    const size_t WBF_BYTES  = (size_t)N2_ * E_ * 2;        // 196,608
    if (ws_size < XP_BYTES + HBUF_BYTES + BIAS_BYTES + WBF_BYTES) return;

    char* ws = (char*)d_ws;
    float*  xp   = (float*)ws;
    float*  hbuf = (float*)(ws + XP_BYTES);
    float*  bias = (float*)(ws + XP_BYTES + HBUF_BYTES);
    bf16_t* Wbf  = (bf16_t*)(ws + XP_BYTES + HBUF_BYTES + BIAS_BYTES);

    prep_kernel<<<384, 256, 0, stream>>>(Wihf, Wihb, bihf, bihb, Wbf, bias);
    dim3 pg((B_ * T_) / 64, 2);
    proj_kernel<<<pg, 256, 0, stream>>>(x, Wbf, bias, xp);
    gru_rec_kernel<<<B_ * 2, 64, 0, stream>>>(xp, srcl, Whhf, bhhf, Whhb, bhhb, hbuf);
    fc_kernel<<<B_, 192, 0, stream>>>(hbuf, fcW, fcb, out);
}

// Round 2
// 566.743 us; speedup vs baseline: 1.4581x; 1.4581x over previous
//
#include <hip/hip_runtime.h>
#include <hip/hip_bf16.h>
#include <cstddef>
#include <cstdint>

// ---------------------------------------------------------------- types
typedef __bf16 bf16_t;
typedef __attribute__((ext_vector_type(8))) __bf16 bf16x8;
typedef __attribute__((ext_vector_type(4))) float f32x4;
typedef __attribute__((ext_vector_type(2))) unsigned u32x2;

#define B_  64
#define T_  2048
#define E_  512
#define H_  32
#define G_  96          // 3*H
#define N2_ 192         // both directions
#define OUT_ 131

// gate prescale constants (baked into xp, W_hh, b_hh):
//  r,z: multiply by C1 = -log2(e)  -> sigmoid(a) = rcp(1+exp2(C1*a))
//  n:   multiply by C2 = 2*log2(e) -> tanh(y)    = 1-2*rcp(1+exp2(C2*y))
#define C1_ (-1.44269504088896340736f)
#define C2_ ( 2.88539008177792681472f)

// ---------------------------------------------------------------- prep: W_ih -> bf16, pack biases
__global__ void prep_kernel(const float* __restrict__ Wf, const float* __restrict__ Wb,
                            const float* __restrict__ bf_, const float* __restrict__ bb_,
                            bf16_t* __restrict__ Wbf, float* __restrict__ bias) {
    int idx = blockIdx.x * 256 + threadIdx.x;        // 0 .. 98303
    int g = idx >> 9, k = idx & 511;
    float v = (g < G_) ? Wf[g * E_ + k] : Wb[(g - G_) * E_ + k];
    Wbf[idx] = (bf16_t)v;
    if (idx < N2_) bias[idx] = (idx < G_) ? bf_[idx] : bb_[idx - G_];
}

// ---------------------------------------------------------------- projection GEMM
// xp[m][n] = scale(n) * (sum_k x[m][k]*W[n][k] + bias[n])
__global__ __launch_bounds__(256) void proj_kernel(
    const float* __restrict__ x,        // [131072][512] f32
    const bf16_t* __restrict__ Wbf,     // [192][512] bf16
    const float* __restrict__ bias,     // [192]
    float* __restrict__ xp)             // [131072][192] f32 (prescaled)
{
    __shared__ bf16_t Alds[64][72];
    __shared__ bf16_t Blds[96][72];

    const int tid  = threadIdx.x;
    const int lane = tid & 63;
    const int w    = tid >> 6;
    const int wm   = w & 1;
    const int wn   = w >> 1;
    const int m0   = blockIdx.x * 64;
    const int n0   = blockIdx.y * 96;

    const int arow = tid >> 2;
    const int acol = (tid & 3) * 16;

    f32x4 acc[2][3];
    #pragma unroll
    for (int i = 0; i < 2; ++i)
        #pragma unroll
        for (int jn = 0; jn < 3; ++jn)
            acc[i][jn] = (f32x4){0.f, 0.f, 0.f, 0.f};

    for (int kt = 0; kt < 8; ++kt) {
        const int c0 = kt * 64;
        __syncthreads();
        {
            const float* asrc = x + (size_t)(m0 + arow) * E_ + c0 + acol;
            float4 v0 = *(const float4*)(asrc + 0);
            float4 v1 = *(const float4*)(asrc + 4);
            float4 v2 = *(const float4*)(asrc + 8);
            float4 v3 = *(const float4*)(asrc + 12);
            bf16x8 pa, pb;
            pa[0]=(bf16_t)v0.x; pa[1]=(bf16_t)v0.y; pa[2]=(bf16_t)v0.z; pa[3]=(bf16_t)v0.w;
            pa[4]=(bf16_t)v1.x; pa[5]=(bf16_t)v1.y; pa[6]=(bf16_t)v1.z; pa[7]=(bf16_t)v1.w;
            pb[0]=(bf16_t)v2.x; pb[1]=(bf16_t)v2.y; pb[2]=(bf16_t)v2.z; pb[3]=(bf16_t)v2.w;
            pb[4]=(bf16_t)v3.x; pb[5]=(bf16_t)v3.y; pb[6]=(bf16_t)v3.z; pb[7]=(bf16_t)v3.w;
            *(bf16x8*)&Alds[arow][acol]     = pa;
            *(bf16x8*)&Alds[arow][acol + 8] = pb;
        }
        #pragma unroll
        for (int i = 0; i < 3; ++i) {
            int u = tid + i * 256;
            int brow = u >> 3, koff = (u & 7) * 8;
            bf16x8 bv = *(const bf16x8*)(Wbf + (size_t)(n0 + brow) * E_ + c0 + koff);
            *(bf16x8*)&Blds[brow][koff] = bv;
        }
        __syncthreads();
        #pragma unroll
        for (int ks = 0; ks < 2; ++ks) {
            bf16x8 af[2], bfr[3];
            #pragma unroll
            for (int i = 0; i < 2; ++i)
                af[i] = *(const bf16x8*)&Alds[wm * 32 + i * 16 + (lane & 15)][ks * 32 + (lane >> 4) * 8];
            #pragma unroll
            for (int jn = 0; jn < 3; ++jn)
                bfr[jn] = *(const bf16x8*)&Blds[wn * 48 + jn * 16 + (lane & 15)][ks * 32 + (lane >> 4) * 8];
            #pragma unroll
            for (int i = 0; i < 2; ++i)
                #pragma unroll
                for (int jn = 0; jn < 3; ++jn)
                    acc[i][jn] = __builtin_amdgcn_mfma_f32_16x16x32_bf16(af[i], bfr[jn], acc[i][jn], 0, 0, 0);
        }
    }
    #pragma unroll
    for (int i = 0; i < 2; ++i)
        #pragma unroll
        for (int jn = 0; jn < 3; ++jn)
            #pragma unroll
            for (int r = 0; r < 4; ++r) {
                int mg = m0 + wm * 32 + i * 16 + (lane >> 4) * 4 + r;
                int ng = n0 + wn * 48 + jn * 16 + (lane & 15);
                int lg = (ng >= 96) ? ng - 96 : ng;
                float scl = (lg < 64) ? C1_ : C2_;
                xp[(size_t)mg * N2_ + ng] = scl * (acc[i][jn][r] + bias[ng]);
            }
}

// ---------------------------------------------------------------- GRU recurrence (all-VALU step)
// 1 wave per chain. lane l: output j=(l&15)+16*(l>>5) (duplicated over row pairs),
// k-half p=(l>>4)&1. Rotating register vrot holds h[16p + ((l&15)+s*i)&15].
__global__ __launch_bounds__(64) void gru_rec_kernel(
    const float* __restrict__ xp,       // [B*T*192] prescaled
    const int*   __restrict__ src_len,  // [B]
    const float* __restrict__ Whh_f, const float* __restrict__ bhh_f,
    const float* __restrict__ Whh_b, const float* __restrict__ bhh_b,
    float* __restrict__ hout)           // [B][64]  (fwd 0..31, bwd 32..63)
{
    const int blk  = blockIdx.x;
    const int b    = blk >> 1;
    const int dir  = blk & 1;
    const int l    = threadIdx.x;
    const int l15  = l & 15;
    const int p    = (l >> 4) & 1;
    const int j    = l15 + 16 * (l >> 5);

    const float* Whh = dir ? Whh_b : Whh_f;
    const float* bhh = dir ? bhh_b : bhh_f;

    // ---- probe DPP row_ror:1 direction: lane sees h-index (l15 + s*i)&15
    int s_dir;
    {
        int q1 = __builtin_amdgcn_update_dpp(l15, l15, 0x121, 0xf, 0xf, false);
        s_dir = (__builtin_amdgcn_readfirstlane(q1) == 1) ? 1 : -1;
    }

    // ---- diagonal prescaled weights
    float wr[16], wz[16], wn[16];
    #pragma unroll
    for (int i = 0; i < 16; ++i) {
        int k = 16 * p + ((l15 + s_dir * i) & 15);
        wr[i] = C1_ * Whh[(j)      * H_ + k];
        wz[i] = C1_ * Whh[(32 + j) * H_ + k];
        wn[i] = C2_ * Whh[(64 + j) * H_ + k];
    }
    const float brh = 0.5f * C1_ * bhh[j];
    const float bzh = 0.5f * C1_ * bhh[32 + j];
    const float bnh = 0.5f * C2_ * bhh[64 + j];

#if __has_builtin(__builtin_amdgcn_permlane32_swap)
    // ---- probe permlane32_swap convention (convention-proof rearrange)
    bool m0c, m1c;
    {
        unsigned xg = (unsigned)(l >> 5);
        u32x2 pr = __builtin_amdgcn_permlane32_swap(xg, xg, false, false);
        unsigned ag = pr.x;
        unsigned d  = (unsigned)p;
        m0c = (xg == d);
        m1c = (ag == d);
    }
#endif

    int len = src_len[b];
    if (len < 1) len = 1;
    if (len > T_) len = T_;
    len = __builtin_amdgcn_readfirstlane(len);
    const int sd = dir ? -1 : 1;
    const int t0 = dir ? (len - 1) : 0;
    const float* colp = xp + (size_t)b * (T_ * N2_) + dir * G_ + j;

    float hval = 0.0f;    // own h[j]
    float vrot = 0.0f;    // broadcast-layout h value

    auto loadq = [&](int q, float& xr, float& xz, float& xn) {
        int qq = (q < len) ? q : (len - 1);
        int t  = t0 + sd * qq;
        const float* ps = colp + (size_t)t * N2_;
        xr = ps[0]; xz = ps[32]; xn = ps[64];
    };

    auto pl16sum = [&](float a) -> float {
#if __has_builtin(__builtin_amdgcn_permlane16_swap)
        u32x2 rr = __builtin_amdgcn_permlane16_swap(__float_as_uint(a), __float_as_uint(a), false, false);
        return __uint_as_float(rr.x) + __uint_as_float(rr.y);
#else
        return a + __int_as_float(__builtin_amdgcn_ds_bpermute((l ^ 16) << 2, __float_as_int(a)));
#endif
    };

    auto step = [&](float xr, float xz, float xn) {
        // ---- 16-deep half-dot with rotating h
        float cur = vrot;
        float ar = brh, az = bzh, an = bnh;
        #pragma unroll
        for (int i = 0; i < 16; ++i) {
            if (i) cur = __int_as_float(__builtin_amdgcn_update_dpp(
                        __float_as_int(cur), __float_as_int(cur), 0x121, 0xf, 0xf, false));
            ar = __builtin_fmaf(cur, wr[i], ar);
            az = __builtin_fmaf(cur, wz[i], az);
            an = __builtin_fmaf(cur, wn[i], an);
        }
        // ---- adjacent-row-pair reduce (k-halves)
        float arf = pl16sum(ar) + xr;       // C1*(xr + hr)
        float azf = pl16sum(az) + xz;       // C1*(xz + hz)
        float anf = pl16sum(an);            // C2*hn
        // ---- gates
        float er = __builtin_amdgcn_exp2f(arf);
        float r  = __builtin_amdgcn_rcpf(1.0f + er);        // sigmoid
        float ez = __builtin_amdgcn_exp2f(azf);
        float z  = __builtin_amdgcn_rcpf(1.0f + ez);        // sigmoid
        float na = __builtin_fmaf(r, anf, xn);               // C2*(xn + r*hn)
        float eu = __builtin_amdgcn_exp2f(na);
        float u  = __builtin_amdgcn_rcpf(1.0f + eu);        // n = 1-2u
        // h' = z*h + (1-z)*n = z*(h + ez*n) = z*fma(-2ez, u, h+ez)
        float hpe = hval + ez;
        float t2  = __builtin_fmaf(-2.0f * ez, u, hpe);
        hval = z * t2;
        // ---- rearrange h' into broadcast layout for next step
#if __has_builtin(__builtin_amdgcn_permlane32_swap)
        u32x2 sw = __builtin_amdgcn_permlane32_swap(__float_as_uint(hval), __float_as_uint(hval), false, false);
        float av = __uint_as_float(sw.x);
        float bv = __uint_as_float(sw.y);
        float ts = m1c ? av : bv;
        vrot = m0c ? hval : ts;
#else
        vrot = __int_as_float(__builtin_amdgcn_ds_bpermute((l15 + 32 * p) << 2, __float_as_int(hval)));
#endif
    };

    // ---- 4-deep software pipeline, static register buffers
    float bxr[4], bxz[4], bxn[4];
    #pragma unroll
    for (int d = 0; d < 4; ++d) loadq(d, bxr[d], bxz[d], bxn[d]);
    int s = 0;
    while (s + 4 <= len) {
        #pragma unroll
        for (int d = 0; d < 4; ++d) {
            step(bxr[d], bxz[d], bxn[d]);
            loadq(s + d + 4, bxr[d], bxz[d], bxn[d]);
        }
        s += 4;
    }
    #pragma unroll
    for (int d = 0; d < 4; ++d)
        if (s + d < len) step(bxr[d], bxz[d], bxn[d]);

    if (p == 0) hout[b * 64 + dir * 32 + j] = hval;
}

// ---------------------------------------------------------------- final fc
__global__ __launch_bounds__(192) void fc_kernel(
    const float* __restrict__ hbuf,     // [64][64]
    const float* __restrict__ fcW,      // [131][64]
    const float* __restrict__ fcb,      // [131]
    float* __restrict__ out)            // [64][131]
{
    __shared__ float hrow[64];
    const int b = blockIdx.x, tid = threadIdx.x;
    if (tid < 64) hrow[tid] = hbuf[b * 64 + tid];
    __syncthreads();
    if (tid < OUT_) {
        float acc = fcb[tid];
        #pragma unroll
        for (int i = 0; i < 64; ++i)
            acc = __builtin_fmaf(hrow[i], fcW[tid * 64 + i], acc);
        out[b * OUT_ + tid] = acc;
    }
}

// ---------------------------------------------------------------- launch
extern "C" void kernel_launch(void* const* d_in, const int* in_sizes, int n_in,
                              void* d_out, int out_size, void* d_ws, size_t ws_size,
                              hipStream_t stream) {
    const float* x    = (const float*)d_in[0];
    const int*   srcl = (const int*)  d_in[1];
    const float* Wihf = (const float*)d_in[3];
    const float* Whhf = (const float*)d_in[4];
    const float* bihf = (const float*)d_in[5];
    const float* bhhf = (const float*)d_in[6];
    const float* Wihb = (const float*)d_in[7];
    const float* Whhb = (const float*)d_in[8];
    const float* bihb = (const float*)d_in[9];
    const float* bhhb = (const float*)d_in[10];
    const float* fcW  = (const float*)d_in[11];
    const float* fcb  = (const float*)d_in[12];
    float* out = (float*)d_out;

    const size_t XP_BYTES   = (size_t)B_ * T_ * N2_ * 4;
    const size_t HBUF_BYTES = (size_t)B_ * 64 * 4;
    const size_t BIAS_BYTES = 1024;
    const size_t WBF_BYTES  = (size_t)N2_ * E_ * 2;
    if (ws_size < XP_BYTES + HBUF_BYTES + BIAS_BYTES + WBF_BYTES) return;

    char* ws = (char*)d_ws;
    float*  xp   = (float*)ws;
    float*  hbuf = (float*)(ws + XP_BYTES);
    float*  bias = (float*)(ws + XP_BYTES + HBUF_BYTES);
    bf16_t* Wbf  = (bf16_t*)(ws + XP_BYTES + HBUF_BYTES + BIAS_BYTES);

    prep_kernel<<<384, 256, 0, stream>>>(Wihf, Wihb, bihf, bihb, Wbf, bias);
    dim3 pg((B_ * T_) / 64, 2);
    proj_kernel<<<pg, 256, 0, stream>>>(x, Wbf, bias, xp);
    gru_rec_kernel<<<B_ * 2, 64, 0, stream>>>(xp, srcl, Whhf, bhhf, Whhb, bhhb, hbuf);
    fc_kernel<<<B_, 192, 0, stream>>>(hbuf, fcW, fcb, out);
}